// Round 1
// 1460.535 us; speedup vs baseline: 1.0369x; 1.0369x over previous
//
#include <hip/hip_runtime.h>
#include <math.h>

// Multislice gradient step. 1024-pt complex fp32 FFT as 3 register-radix-8
// phases (fused radix-2 stages 0-2 / 3-5 / 6-9) with ping-pong LDS exchanges.
// R1: coalesced k_T/k_merge (lane == float4 index, no 128-B lane stride) and
// global-load hoisting in all FFT kernels (km/Tz/meas/Tg/srcB issued at kernel
// start so HBM latency overlaps the first FFT phase instead of being exposed
// serially in later barrier regions).

#define NN (1024*1024)
#define KAPPA 40.840704496667314f
#define TWO_PI_F 6.2831853071795865f
#define DFX_D 0.0030048076923076925
#define RRCUT 187177
#define F(i) ((i) + ((i)>>4))

#define JT 0
#define JT_WP 1
#define JN 2
#define JRESID 3

__device__ __forceinline__ float2 cmulf(float2 a, float2 b){
    return make_float2(a.x*b.x - a.y*b.y, a.x*b.y + a.y*b.x);
}
__device__ __forceinline__ float2 cmulcj(float2 a, float2 b){ // a * conj(b)
    return make_float2(a.x*b.x + a.y*b.y, a.y*b.x - a.x*b.y);
}
__device__ __forceinline__ float2 f2add(float2 a, float2 b){ return make_float2(a.x+b.x, a.y+b.y); }
__device__ __forceinline__ float2 f2sub(float2 a, float2 b){ return make_float2(a.x-b.x, a.y-b.y); }

__device__ __forceinline__ void fill_tw(float2* tw, int tid){
    #pragma unroll
    for (int k = tid; k < 512; k += 256){
        float s, c; sincosf(-(float)k * (TWO_PI_F/1024.0f), &s, &c);
        tw[k] = make_float2(c, s);
    }
}

// ---------- register phase kernels (positions tracked per comments) ----------
// DIF phase1: stages half=512,256,128 on elements at positions lane+128k
__device__ __forceinline__ void dif_ph1(float2 r[8], const float2* tw, int lane){
    float2 a, d;
    #pragma unroll
    for (int k=0;k<4;++k){
        a=r[k]; d=f2sub(r[k],r[k+4]);
        r[k]=f2add(a,r[k+4]);
        r[k+4]=cmulf(d, tw[lane+128*k]);
    }
    float2 w20 = tw[lane<<1], w21 = tw[(lane+128)<<1];
    a=r[0]; d=f2sub(r[0],r[2]); r[0]=f2add(a,r[2]); r[2]=cmulf(d,w20);
    a=r[1]; d=f2sub(r[1],r[3]); r[1]=f2add(a,r[3]); r[3]=cmulf(d,w21);
    a=r[4]; d=f2sub(r[4],r[6]); r[4]=f2add(a,r[6]); r[6]=cmulf(d,w20);
    a=r[5]; d=f2sub(r[5],r[7]); r[5]=f2add(a,r[7]); r[7]=cmulf(d,w21);
    float2 w3 = tw[lane<<2];
    a=r[0]; d=f2sub(r[0],r[1]); r[0]=f2add(a,r[1]); r[1]=cmulf(d,w3);
    a=r[2]; d=f2sub(r[2],r[3]); r[2]=f2add(a,r[3]); r[3]=cmulf(d,w3);
    a=r[4]; d=f2sub(r[4],r[5]); r[4]=f2add(a,r[5]); r[5]=cmulf(d,w3);
    a=r[6]; d=f2sub(r[6],r[7]); r[6]=f2add(a,r[7]); r[7]=cmulf(d,w3);
}
// DIT phase1': stages half=128,256,512 (inverse of dif_ph1)
__device__ __forceinline__ void dit_ph1(float2 r[8], const float2* tw, int lane){
    float2 a, b;
    float2 w3 = tw[lane<<2];
    a=r[0]; b=cmulcj(r[1],w3); r[0]=f2add(a,b); r[1]=f2sub(a,b);
    a=r[2]; b=cmulcj(r[3],w3); r[2]=f2add(a,b); r[3]=f2sub(a,b);
    a=r[4]; b=cmulcj(r[5],w3); r[4]=f2add(a,b); r[5]=f2sub(a,b);
    a=r[6]; b=cmulcj(r[7],w3); r[6]=f2add(a,b); r[7]=f2sub(a,b);
    float2 w20 = tw[lane<<1], w21 = tw[(lane+128)<<1];
    a=r[0]; b=cmulcj(r[2],w20); r[0]=f2add(a,b); r[2]=f2sub(a,b);
    a=r[1]; b=cmulcj(r[3],w21); r[1]=f2add(a,b); r[3]=f2sub(a,b);
    a=r[4]; b=cmulcj(r[6],w20); r[4]=f2add(a,b); r[6]=f2sub(a,b);
    a=r[5]; b=cmulcj(r[7],w21); r[5]=f2add(a,b); r[7]=f2sub(a,b);
    #pragma unroll
    for (int k=0;k<4;++k){
        a=r[k]; b=cmulcj(r[k+4], tw[lane+128*k]);
        r[k]=f2add(a,b); r[k+4]=f2sub(a,b);
    }
}
// DIF phase2: stages half=64,32,16 on elements at positions 128b+m0+16k
__device__ __forceinline__ void dif_ph2(float2 r[8], const float2* tw, int m0){
    float2 a, d;
    #pragma unroll
    for (int k=0;k<4;++k){
        a=r[k]; d=f2sub(r[k],r[k+4]);
        r[k]=f2add(a,r[k+4]);
        r[k+4]=cmulf(d, tw[(m0+16*k)<<3]);
    }
    float2 w40 = tw[m0<<4], w41 = tw[(m0+16)<<4];
    a=r[0]; d=f2sub(r[0],r[2]); r[0]=f2add(a,r[2]); r[2]=cmulf(d,w40);
    a=r[1]; d=f2sub(r[1],r[3]); r[1]=f2add(a,r[3]); r[3]=cmulf(d,w41);
    a=r[4]; d=f2sub(r[4],r[6]); r[4]=f2add(a,r[6]); r[6]=cmulf(d,w40);
    a=r[5]; d=f2sub(r[5],r[7]); r[5]=f2add(a,r[7]); r[7]=cmulf(d,w41);
    float2 w5 = tw[m0<<5];
    a=r[0]; d=f2sub(r[0],r[1]); r[0]=f2add(a,r[1]); r[1]=cmulf(d,w5);
    a=r[2]; d=f2sub(r[2],r[3]); r[2]=f2add(a,r[3]); r[3]=cmulf(d,w5);
    a=r[4]; d=f2sub(r[4],r[5]); r[4]=f2add(a,r[5]); r[5]=cmulf(d,w5);
    a=r[6]; d=f2sub(r[6],r[7]); r[6]=f2add(a,r[7]); r[7]=cmulf(d,w5);
}
// DIT phase2': stages half=16,32,64
__device__ __forceinline__ void dit_ph2(float2 r[8], const float2* tw, int m0){
    float2 a, b;
    float2 w5 = tw[m0<<5];
    a=r[0]; b=cmulcj(r[1],w5); r[0]=f2add(a,b); r[1]=f2sub(a,b);
    a=r[2]; b=cmulcj(r[3],w5); r[2]=f2add(a,b); r[3]=f2sub(a,b);
    a=r[4]; b=cmulcj(r[5],w5); r[4]=f2add(a,b); r[5]=f2sub(a,b);
    a=r[6]; b=cmulcj(r[7],w5); r[6]=f2add(a,b); r[7]=f2sub(a,b);
    float2 w40 = tw[m0<<4], w41 = tw[(m0+16)<<4];
    a=r[0]; b=cmulcj(r[2],w40); r[0]=f2add(a,b); r[2]=f2sub(a,b);
    a=r[1]; b=cmulcj(r[3],w41); r[1]=f2add(a,b); r[3]=f2sub(a,b);
    a=r[4]; b=cmulcj(r[6],w40); r[4]=f2add(a,b); r[6]=f2sub(a,b);
    a=r[5]; b=cmulcj(r[7],w41); r[5]=f2add(a,b); r[7]=f2sub(a,b);
    #pragma unroll
    for (int k=0;k<4;++k){
        a=r[k]; b=cmulcj(r[k+4], tw[(m0+16*k)<<3]);
        r[k]=f2add(a,b); r[k+4]=f2sub(a,b);
    }
}
// radix-8 tail: DIF stages half=4,2,1 on 8 consecutive elems (verified R2)
__device__ __forceinline__ void dif_reg(float2 r[8]){
    const float C = 0.70710678118654752f;
    float2 a,d;
    a=r[0]; d=f2sub(r[0],r[4]); r[0]=f2add(a,r[4]); r[4]=d;
    a=r[1]; d=f2sub(r[1],r[5]); r[1]=f2add(a,r[5]); r[5]=make_float2(C*(d.x+d.y), C*(d.y-d.x));
    a=r[2]; d=f2sub(r[2],r[6]); r[2]=f2add(a,r[6]); r[6]=make_float2(d.y, -d.x);
    a=r[3]; d=f2sub(r[3],r[7]); r[3]=f2add(a,r[7]); r[7]=make_float2(C*(d.y-d.x), -C*(d.x+d.y));
    a=r[0]; r[0]=f2add(a,r[2]); r[2]=f2sub(a,r[2]);
    a=r[1]; d=f2sub(r[1],r[3]); r[1]=f2add(a,r[3]); r[3]=make_float2(d.y,-d.x);
    a=r[4]; r[4]=f2add(a,r[6]); r[6]=f2sub(a,r[6]);
    a=r[5]; d=f2sub(r[5],r[7]); r[5]=f2add(a,r[7]); r[7]=make_float2(d.y,-d.x);
    a=r[0]; r[0]=f2add(a,r[1]); r[1]=f2sub(a,r[1]);
    a=r[2]; r[2]=f2add(a,r[3]); r[3]=f2sub(a,r[3]);
    a=r[4]; r[4]=f2add(a,r[5]); r[5]=f2sub(a,r[5]);
    a=r[6]; r[6]=f2add(a,r[7]); r[7]=f2sub(a,r[7]);
}
// radix-8 head: DIT stages half=1,2,4 (verified R2)
__device__ __forceinline__ void dit_reg(float2 r[8]){
    const float C = 0.70710678118654752f;
    float2 a,b,t;
    a=r[0]; r[0]=f2add(a,r[1]); r[1]=f2sub(a,r[1]);
    a=r[2]; r[2]=f2add(a,r[3]); r[3]=f2sub(a,r[3]);
    a=r[4]; r[4]=f2add(a,r[5]); r[5]=f2sub(a,r[5]);
    a=r[6]; r[6]=f2add(a,r[7]); r[7]=f2sub(a,r[7]);
    a=r[0]; r[0]=f2add(a,r[2]); r[2]=f2sub(a,r[2]);
    a=r[1]; t=r[3]; b=make_float2(-t.y, t.x); r[1]=f2add(a,b); r[3]=f2sub(a,b);
    a=r[4]; r[4]=f2add(a,r[6]); r[6]=f2sub(a,r[6]);
    a=r[5]; t=r[7]; b=make_float2(-t.y, t.x); r[5]=f2add(a,b); r[7]=f2sub(a,b);
    a=r[0]; r[0]=f2add(a,r[4]); r[4]=f2sub(a,r[4]);
    a=r[1]; t=r[5]; b=make_float2(C*(t.x-t.y), C*(t.x+t.y)); r[1]=f2add(a,b); r[5]=f2sub(a,b);
    a=r[2]; t=r[6]; b=make_float2(-t.y, t.x); r[2]=f2add(a,b); r[6]=f2sub(a,b);
    a=r[3]; t=r[7]; b=make_float2(-C*(t.x+t.y), C*(t.x-t.y)); r[3]=f2add(a,b); r[7]=f2sub(a,b);
}

// ---------- LDS exchange helpers (ro = row*1024 position offset) ----------
__device__ __forceinline__ void st128l(float2* L, int ro, int lane, const float2 r[8]){
    #pragma unroll
    for (int k=0;k<8;++k) L[F(ro + lane + 128*k)] = r[k];
}
__device__ __forceinline__ void ld128l(const float2* L, int ro, int lane, float2 r[8]){
    #pragma unroll
    for (int k=0;k<8;++k) r[k] = L[F(ro + lane + 128*k)];
}
__device__ __forceinline__ void st16l(float2* L, int ro, int lane, const float2 r[8]){
    int b = lane>>4, m0 = lane&15, q = ro + 128*b + m0;
    #pragma unroll
    for (int k=0;k<8;++k) L[F(q + 16*k)] = r[k];
}
__device__ __forceinline__ void ld16l(const float2* L, int ro, int lane, float2 r[8]){
    int b = lane>>4, m0 = lane&15, q = ro + 128*b + m0;
    #pragma unroll
    for (int k=0;k<8;++k) r[k] = L[F(q + 16*k)];
}
__device__ __forceinline__ void st8l(float2* L, int ro, int lane, const float2 r[8]){
    int q = ro + 8*lane;
    #pragma unroll
    for (int i=0;i<8;++i) L[F(q + i)] = r[i];
}
// read after st8l state, fold DIF stage half=8, leaves 8 consecutive (pos 8*lane+i)
__device__ __forceinline__ void ldfold_dif(const float2* L, int ro, int lane,
                                           const float2* tw, float2 r[8]){
    int rr = lane>>1, sub = lane&1, q = ro + 16*rr;
    #pragma unroll
    for (int i=0;i<8;++i){
        float2 x = L[F(q + i)];
        float2 y = L[F(q + 8 + i)];
        r[i] = sub ? cmulf(f2sub(x,y), tw[i<<6]) : f2add(x,y);
    }
}
// read after st8l state, fold DIT stage half=8, leaves stride-16 (pos 128b+m0+16k)
__device__ __forceinline__ void ldfold_dit(const float2* L, int ro, int lane,
                                           const float2* tw, float2 r[8]){
    int b = lane>>4, m0 = lane&15, m0s = m0&7;
    float2 w = tw[m0s<<6];
    int q = ro + 128*b + m0s;
    #pragma unroll
    for (int k=0;k<8;++k){
        float2 x = L[F(q + 16*k)];
        float2 y = L[F(q + 16*k + 8)];
        float2 bb = cmulcj(y, w);
        r[k] = (m0 < 8) ? f2add(x,bb) : f2sub(x,bb);
    }
}
__device__ __forceinline__ void load8g(const float2* src, int lane, float2 r[8]){
    const float4* s4 = (const float4*)src + lane*4;
    #pragma unroll
    for (int m=0;m<4;++m){
        float4 v = s4[m];
        r[2*m]   = make_float2(v.x, v.y);
        r[2*m+1] = make_float2(v.z, v.w);
    }
}
__device__ __forceinline__ void twrite2(const float2* L, int tid, float2* dst,
                                        int r0, float s){
    #pragma unroll
    for (int k=0;k<4;++k){
        int c = tid + (k<<8);
        float2 a0 = L[F(c)], a1 = L[F(1024+c)];
        ((float4*)(dst + ((size_t)c<<10) + r0))[0] =
            make_float4(a0.x*s, a0.y*s, a1.x*s, a1.y*s);
    }
}

// ---------- precompute kernels ----------
__global__ void __launch_bounds__(256) k_kern(float2* __restrict__ kp,
                                              float2* __restrict__ kf){
    int idx = blockIdx.x*256 + threadIdx.x;
    int j = idx >> 10, i = idx & 1023;
    int a = __brev((unsigned)i) >> 22;
    int b = __brev((unsigned)j) >> 22;
    int ra = a - (a >= 512 ? 1024 : 0);
    int rb = b - (b >= 512 ? 1024 : 0);
    int rr = ra*ra + rb*rb;
    float2 p = make_float2(0.f,0.f), f = make_float2(0.f,0.f);
    if (rr <= RRCUT){
        double urr = (double)rr * (DFX_D*DFX_D);
        double kz = sqrt(4.0 - urr);
        double s1,c1,s2,c2;
        sincos(6.283185307179586 * 3.25    * kz, &s1, &c1);
        sincos(6.283185307179586 * -24.375 * kz, &s2, &c2);
        p = make_float2((float)c1,(float)s1);
        f = make_float2((float)c2,(float)s2);
    }
    kp[idx] = p; kf[idx] = f;
}

// Coalesced k_T: one thread per (pixel, z-quad). The two float4 loads of a
// wave pair up into fully-used contiguous lines; T stores are 4 coalesced
// 128-B plane chunks per wave instruction (vs. 128-B lane stride before).
__global__ void __launch_bounds__(256) k_T(const float4* __restrict__ x,
                                           float2* __restrict__ T){
    int idx = blockIdx.x*256 + threadIdx.x;   // 0 .. 4M-1
    int p = idx >> 2;                          // pixel
    int q = idx & 3;                           // z-quad
    float4 vr = x[(size_t)p*8 + q];            // real z = 4q..4q+3
    float4 vi = x[(size_t)p*8 + 4 + q];        // imag z = 4q..4q+3
    const float* fr = (const float*)&vr;
    const float* fi = (const float*)&vi;
    #pragma unroll
    for (int j=0;j<4;++j){
        int z = 4*q + j;
        float amp = __expf(-KAPPA*fi[j]);
        float s, c; __sincosf(KAPPA*fr[j], &s, &c);
        T[(size_t)z*NN + p] = make_float2(amp*c, amp*s);
    }
}

// ---------- chain head: u = planewave*T0, row DIF, transposed write ----------
__global__ void __launch_bounds__(256) k_head(float2* __restrict__ dst,
                                              const float2* __restrict__ T0,
                                              const float* __restrict__ nail){
    __shared__ float2 A[2176], B[2176], tw[512];
    const int tid = threadIdx.x;
    fill_tw(tw, tid);
    const int row = tid>>7, lane = tid&127, ro = row<<10, m0 = lane&15;
    const int r0 = blockIdx.x*2;
    const size_t gbase = ((size_t)(r0+row))<<10;
    float dfx = (float)DFX_D;
    float t0 = rintf(nail[0]*2.0f/dfx)*dfx;
    float t1 = rintf(nail[1]*2.0f/dfx)*dfx;
    float yv = (float)((r0+row) - 512) * 0.325f;
    float2 r[8];
    #pragma unroll
    for (int k=0;k<8;++k){
        int col = lane + 128*k;
        float2 tv = T0[gbase + col];
        float xv = (float)(col - 512) * 0.325f;
        float s0, c0; sincosf(TWO_PI_F*(t0*xv + t1*yv), &s0, &c0);
        r[k] = cmulf(make_float2(c0,s0), tv);
    }
    __syncthreads();                       // tw ready
    dif_ph1(r, tw, lane);
    st128l(A, ro, lane, r); __syncthreads();
    ld16l(A, ro, lane, r); dif_ph2(r, tw, m0);
    st16l(B, ro, lane, r); __syncthreads();
    ldfold_dif(B, ro, lane, tw, r); dif_reg(r);
    st8l(A, ro, lane, r); __syncthreads();
    twrite2(A, tid, dst, r0, 1.0f);
}

// ---------- pass2: col DIF + kern-mult (bitrev) + col DIT, transposed ----------
__global__ void __launch_bounds__(256) k_pass2(
    const float2* __restrict__ srcA, float2* __restrict__ dstA,
    const float2* __restrict__ srcB, float2* __restrict__ dstB,
    const float2* __restrict__ km, int conj, int pupil)
{
    __shared__ float2 A[2176], B[2176], tw[512];
    const int tid = threadIdx.x;
    fill_tw(tw, tid);
    const int row = tid>>7, lane = tid&127, ro = row<<10, m0 = lane&15;
    int bid = blockIdx.x;
    const float2* src = srcA; float2* dst = dstA;
    if (srcB != nullptr && bid >= 512){ src = srcB; dst = dstB; bid -= 512; }
    const int r0 = bid*2;
    const int jrow = r0 + row;
    const float2* srcR = src + (((size_t)r0)<<10) + ro;
    float2 r[8];
    #pragma unroll
    for (int k=0;k<8;++k) r[k] = srcR[lane + 128*k];
    // hoisted km prefetch: overlaps HBM latency with dif phases
    float4 kv[4];
    if (!pupil){
        const float4* k4 = (const float4*)(km + (((size_t)jrow)<<10)) + lane*4;
        #pragma unroll
        for (int m=0;m<4;++m) kv[m] = k4[m];
    }
    __syncthreads();                       // tw ready
    dif_ph1(r, tw, lane);
    st128l(A, ro, lane, r); __syncthreads();
    ld16l(A, ro, lane, r); dif_ph2(r, tw, m0);
    st16l(B, ro, lane, r); __syncthreads();
    ldfold_dif(B, ro, lane, tw, r); dif_reg(r);
    // pointwise at bitrev positions 8*lane+i of row jrow
    if (pupil){
        int bb = __brev((unsigned)jrow) >> 22;
        int rb = bb - (bb >= 512 ? 1024 : 0);
        int rb2 = rb*rb;
        #pragma unroll
        for (int i=0;i<8;++i){
            int aa = __brev((unsigned)(8*lane+i)) >> 22;
            int ra = aa - (aa >= 512 ? 1024 : 0);
            if (ra*ra + rb2 > RRCUT) r[i] = make_float2(0.f,0.f);
        }
    } else {
        float sg = conj ? -1.0f : 1.0f;
        #pragma unroll
        for (int m=0;m<4;++m){
            r[2*m]   = cmulf(r[2*m],   make_float2(kv[m].x, sg*kv[m].y));
            r[2*m+1] = cmulf(r[2*m+1], make_float2(kv[m].z, sg*kv[m].w));
        }
    }
    dit_reg(r);
    st8l(A, ro, lane, r); __syncthreads();
    ldfold_dit(A, ro, lane, tw, r); dit_ph2(r, tw, m0);
    st16l(B, ro, lane, r); __syncthreads();
    ld128l(B, ro, lane, r); dit_ph1(r, tw, lane);
    st128l(A, ro, lane, r); __syncthreads();
    twrite2(A, tid, dst, r0, 1.0f/1024.0f);
}

// ---------- fused junction: row DIT + pointwise + row DIF ----------
__global__ void __launch_bounds__(256) k_junc(
    const float2* __restrict__ src, float2* __restrict__ dst,
    const float2* __restrict__ Tz, float2* __restrict__ wp,
    const float* __restrict__ meas, int mode)
{
    __shared__ float2 A[2176], B[2176], tw[512];
    const int tid = threadIdx.x;
    fill_tw(tw, tid);
    const int row = tid>>7, lane = tid&127, ro = row<<10, m0 = lane&15;
    const int r0 = blockIdx.x*2;
    const size_t gbase = ((size_t)(r0+row))<<10;
    const float S = 1.0f/1024.0f;
    float2 r[8];
    load8g(src + (((size_t)r0)<<10) + ro, lane, r);
    // hoisted pointwise-operand prefetch (Tz or meas)
    float2 pre[8];
    if (mode == JT || mode == JT_WP){
        #pragma unroll
        for (int k=0;k<8;++k) pre[k] = Tz[gbase + lane + 128*k];
    } else if (mode == JRESID){
        #pragma unroll
        for (int k=0;k<8;++k) pre[k].x = meas[gbase + lane + 128*k];
    }
    dit_reg(r);
    st8l(A, ro, lane, r); __syncthreads();
    ldfold_dit(A, ro, lane, tw, r); dit_ph2(r, tw, m0);
    st16l(B, ro, lane, r); __syncthreads();
    ld128l(B, ro, lane, r); dit_ph1(r, tw, lane);
    #pragma unroll
    for (int k=0;k<8;++k){
        size_t g = gbase + lane + 128*k;
        float2 v = make_float2(S*r[k].x, S*r[k].y);
        if (mode == JT || mode == JT_WP){
            v = cmulf(v, pre[k]);
            if (mode == JT_WP) wp[g] = v;
        } else if (mode == JRESID){
            float m = pre[k].x;
            float aamp = fmaxf(sqrtf(v.x*v.x + v.y*v.y), 1e-30f);
            float f = 1.0f - sqrtf(m)/aamp;
            v.x *= f; v.y *= f;
        }
        r[k] = v;
    }
    dif_ph1(r, tw, lane);
    st128l(A, ro, lane, r); __syncthreads();
    ld16l(A, ro, lane, r); dif_ph2(r, tw, m0);
    st16l(B, ro, lane, r); __syncthreads();
    ldfold_dif(B, ro, lane, tw, r); dif_reg(r);
    st8l(A, ro, lane, r); __syncthreads();
    twrite2(A, tid, dst, r0, 1.0f);
}

// ---------- reverse junction: both chains per tile; grad -> T plane ----------
__global__ void __launch_bounds__(256) k_rev(
    const float2* __restrict__ srcU, float2* __restrict__ dstU,
    const float2* __restrict__ srcB, float2* __restrict__ dstB,
    float2* __restrict__ Tz, int headU)
{
    __shared__ float2 A[2176], B[2176], tw[512];
    const int tid = threadIdx.x;
    fill_tw(tw, tid);
    const int row = tid>>7, lane = tid&127, ro = row<<10, m0 = lane&15;
    const int r0 = blockIdx.x*2;
    const size_t gbase = ((size_t)(r0+row))<<10;
    const float S = 1.0f/1024.0f;
    float2 u[8], Tg[8], bb[8], r[8];
    // ---- issue ALL global loads up front (one latency window, not three) ----
    if (!headU){
        load8g(srcU + (((size_t)r0)<<10) + ro, lane, u);
    } else {
        const float2* srcR = srcU + (((size_t)r0)<<10) + ro;
        #pragma unroll
        for (int k=0;k<8;++k) u[k] = srcR[lane + 128*k];
    }
    #pragma unroll
    for (int k=0;k<8;++k) Tg[k] = Tz[gbase + lane + 128*k];
    load8g(srcB + (((size_t)r0)<<10) + ro, lane, bb);
    // ---- U chain: DIT (or direct natural load at head) ----
    if (!headU){
        dit_reg(u);
        st8l(A, ro, lane, u); __syncthreads();
        ldfold_dit(A, ro, lane, tw, u); dit_ph2(u, tw, m0);
        st16l(B, ro, lane, u); __syncthreads();
        ld128l(B, ro, lane, u); dit_ph1(u, tw, lane);
        #pragma unroll
        for (int k=0;k<8;++k){ u[k].x *= S; u[k].y *= S; }
    } else {
        __syncthreads();                   // tw ready for dif_ph1 below
    }
    // divided field (skip at head)
    #pragma unroll
    for (int k=0;k<8;++k){
        if (headU) r[k] = u[k];
        else {
            float inv = 1.0f/(Tg[k].x*Tg[k].x + Tg[k].y*Tg[k].y);
            float2 wc = cmulcj(u[k], Tg[k]);
            r[k] = make_float2(wc.x*inv, wc.y*inv);
        }
    }
    dif_ph1(r, tw, lane);
    st128l(A, ro, lane, r); __syncthreads();
    ld16l(A, ro, lane, r); dif_ph2(r, tw, m0);
    st16l(B, ro, lane, r); __syncthreads();
    ldfold_dif(B, ro, lane, tw, r); dif_reg(r);
    st8l(A, ro, lane, r); __syncthreads();
    twrite2(A, tid, dstU, r0, 1.0f);
    // ---- B chain: DIT (from prefetched bb) ----
    dit_reg(bb);
    st8l(B, ro, lane, bb); __syncthreads();
    ldfold_dit(B, ro, lane, tw, r); dit_ph2(r, tw, m0);
    st16l(A, ro, lane, r); __syncthreads();
    ld128l(A, ro, lane, r); dit_ph1(r, tw, lane);
    // grad emit (into T plane) + premult conj(T)
    #pragma unroll
    for (int k=0;k<8;++k){
        float2 b = make_float2(S*r[k].x, S*r[k].y);
        float2 q = headU ? cmulcj(cmulcj(b, u[k]), Tg[k]) : cmulcj(b, u[k]);
        Tz[gbase + lane + 128*k] = make_float2(KAPPA*q.y, -KAPPA*q.x);
        r[k] = cmulcj(b, Tg[k]);
    }
    dif_ph1(r, tw, lane);
    st128l(B, ro, lane, r); __syncthreads();
    ld16l(B, ro, lane, r); dif_ph2(r, tw, m0);
    st16l(A, ro, lane, r); __syncthreads();
    ldfold_dif(A, ro, lane, tw, r); dif_reg(r);
    st8l(B, ro, lane, r); __syncthreads();
    twrite2(B, tid, dstB, r0, 1.0f);
}

// ---------- tail: finish both chains, grad[0] -> T plane 0 ----------
__global__ void __launch_bounds__(256) k_tail(
    const float2* __restrict__ srcU, const float2* __restrict__ srcB,
    float2* __restrict__ G0)
{
    __shared__ float2 A[2176], B[2176], tw[512];
    const int tid = threadIdx.x;
    fill_tw(tw, tid);
    const int row = tid>>7, lane = tid&127, ro = row<<10, m0 = lane&15;
    const int r0 = blockIdx.x*2;
    const size_t gbase = ((size_t)(r0+row))<<10;
    const float S = 1.0f/1024.0f;
    float2 u[8], r[8];
    load8g(srcU + (((size_t)r0)<<10) + ro, lane, u);
    load8g(srcB + (((size_t)r0)<<10) + ro, lane, r);   // hoisted prefetch
    dit_reg(u);
    st8l(A, ro, lane, u); __syncthreads();
    ldfold_dit(A, ro, lane, tw, u); dit_ph2(u, tw, m0);
    st16l(B, ro, lane, u); __syncthreads();
    ld128l(B, ro, lane, u); dit_ph1(u, tw, lane);
    dit_reg(r);
    st8l(A, ro, lane, r); __syncthreads();
    ldfold_dit(A, ro, lane, tw, r); dit_ph2(r, tw, m0);
    st16l(B, ro, lane, r); __syncthreads();
    ld128l(B, ro, lane, r); dit_ph1(r, tw, lane);
    #pragma unroll
    for (int k=0;k<8;++k){
        float2 b = make_float2(S*r[k].x, S*r[k].y);
        float2 w = make_float2(S*u[k].x, S*u[k].y);
        float2 q = cmulcj(b, w);
        G0[gbase + lane + 128*k] = make_float2(KAPPA*q.y, -KAPPA*q.x);
    }
}

// Coalesced k_merge: one thread per output float4 (p = pixel, c = re/im,
// zb = z-quad). x/out traffic is lane-contiguous; the 4 G loads per thread
// are 8-lane broadcasts that the coalescer merges into full 64-B line fetches.
__global__ void __launch_bounds__(256) k_merge(const float4* __restrict__ x,
                                               const float2* __restrict__ G,
                                               const float* __restrict__ alpha,
                                               float4* __restrict__ out){
    int idx4 = blockIdx.x*256 + threadIdx.x;   // 0 .. 8M-1
    int p  = idx4 >> 3;                        // pixel
    int f  = idx4 & 7;                         // float4 within pixel
    int c  = f >> 2;                           // 0 = real, 1 = imag
    int zb = (f & 3) * 4;                      // z base of this quad
    float al = alpha[0];
    float4 xv = x[idx4];
    float gc[4];
    #pragma unroll
    for (int j=0;j<4;++j){
        float2 g = G[(size_t)(zb + j)*NN + p];
        gc[j] = c ? g.y : g.x;
    }
    out[idx4] = make_float4(xv.x - al*gc[0], xv.y - al*gc[1],
                            xv.z - al*gc[2], xv.w - al*gc[3]);
}

extern "C" void kernel_launch(void* const* d_in, const int* in_sizes, int n_in,
                              void* d_out, int out_size, void* d_ws, size_t ws_size,
                              hipStream_t stream)
{
    const float* x     = (const float*)d_in[0];
    const float* meas  = (const float*)d_in[1];
    const float* nail  = (const float*)d_in[2];
    const float* alpha = (const float*)d_in[3];

    if (ws_size < (size_t)23*NN*sizeof(float2)) return;

    float2* W   = (float2*)d_ws;
    float2* T   = W;                       // 16 planes; grads overwrite in place
    float2* KP  = W + (size_t)16*NN;
    float2* KF  = W + (size_t)17*NN;
    float2* U0  = W + (size_t)18*NN;
    float2* TAB = W + (size_t)19*NN;
    float2* TBB = W + (size_t)20*NN;
    float2* TAU = W + (size_t)21*NN;
    float2* TBU = W + (size_t)22*NN;

    k_kern<<<4096, 256, 0, stream>>>(KP, KF);
    k_T   <<<16384, 256, 0, stream>>>((const float4*)x, T);

    auto P2f = [&](const float2* km, int cj, int pup){
        k_pass2<<<512, 256, 0, stream>>>(TAB, TBB, nullptr, nullptr, km, cj, pup);
    };

    // ---------- forward + backprop mega-chain ----------
    k_head<<<512, 256, 0, stream>>>(TAB, T, nail);
    P2f(KP, 0, 0);
    for (int z = 1; z <= 14; ++z){
        k_junc<<<512, 256, 0, stream>>>(TBB, TAB, T + (size_t)z*NN, nullptr, nullptr, JT);
        P2f(KP, 0, 0);
    }
    k_junc<<<512, 256, 0, stream>>>(TBB, TAB, T + (size_t)15*NN, U0, nullptr, JT_WP);
    P2f(KF, 0, 0);
    k_junc<<<512, 256, 0, stream>>>(TBB, TAB, nullptr, nullptr, nullptr, JN);
    P2f(nullptr, 0, 1);
    k_junc<<<512, 256, 0, stream>>>(TBB, TAB, nullptr, nullptr, meas, JRESID);
    P2f(nullptr, 1, 1);
    k_junc<<<512, 256, 0, stream>>>(TBB, TAB, nullptr, nullptr, nullptr, JN);
    P2f(KF, 1, 0);

    // ---------- reverse loop: paired B/U per tile ----------
    for (int zz = 15; zz >= 1; --zz){
        k_rev<<<512, 256, 0, stream>>>(zz == 15 ? U0 : TBU, TAU, TBB, TAB,
                                       T + (size_t)zz*NN, zz == 15 ? 1 : 0);
        k_pass2<<<1024, 256, 0, stream>>>(TAB, TBB, TAU, TBU, KP, 1, 0);
    }
    k_tail<<<512, 256, 0, stream>>>(TBU, TBB, T);

    // ---------- merge: out = x - alpha*g, straight into d_out ----------
    k_merge<<<32768, 256, 0, stream>>>((const float4*)x, T, alpha, (float4*)d_out);
}